// Round 3
// baseline (333.777 us; speedup 1.0000x reference)
//
#include <hip/hip_runtime.h>
#include <stdint.h>

typedef unsigned short ushort_t;
typedef __attribute__((ext_vector_type(8))) short bf16x8;   // 8 bf16 = 4 VGPRs (MFMA A/B frag)
typedef __attribute__((ext_vector_type(4))) float f32x4;    // MFMA C/D frag / fp32 vec-load

#define BM 256
#define BN 256
#define BK 64
#define SCALING 2.0f

static __device__ __forceinline__ unsigned short f2b(float f) {
    union { float f; unsigned int i; } v;
    v.f = f;
    unsigned int r = 0x7FFFu + ((v.i >> 16) & 1u);   // round-to-nearest-even
    return (unsigned short)((v.i + r) >> 16);
}

// async global->LDS, 16 bytes/lane. HW dest = wave-uniform base + lane*16.
static __device__ __forceinline__ void ld_g2l16(const void* g, void* l) {
    __builtin_amdgcn_global_load_lds(
        (const __attribute__((address_space(1))) void*)g,
        (__attribute__((address_space(3))) void*)l,
        16, 0, 0);
}

#define SFENCE()     __builtin_amdgcn_sched_barrier(0)
#define BARRIER()    do { SFENCE(); __builtin_amdgcn_s_barrier(); SFENCE(); } while (0)
#define WAIT_LGKM0() do { asm volatile("s_waitcnt lgkmcnt(0)" ::: "memory"); SFENCE(); } while (0)
#define WAIT_VM(N)   do { asm volatile("s_waitcnt vmcnt(" #N ")" ::: "memory"); SFENCE(); } while (0)

// ---------------------------------------------------------------------------
// Kernel 1: W_eff[o][d] = W[o][d] + SCALING * sum_r B[o][r]*A[r][d]  (fp32 in, bf16 out RNE)
// ---------------------------------------------------------------------------
__global__ void weff_kernel(const float* __restrict__ W,
                            const float* __restrict__ A,
                            const float* __restrict__ Bm,
                            ushort_t* __restrict__ Weff,
                            int D, int R) {
    int gid = blockIdx.x * blockDim.x + threadIdx.x;
    int perRow = D >> 3;
    if (gid >= D * perRow) return;
    int o  = gid / perRow;
    int d0 = (gid - o * perRow) << 3;

    float br[16];
    for (int r = 0; r < R; ++r) br[r] = SCALING * Bm[(size_t)o * R + r];

    float acc[8];
    #pragma unroll
    for (int j = 0; j < 8; ++j) acc[j] = W[(size_t)o * D + d0 + j];
    for (int r = 0; r < R; ++r) {
        #pragma unroll
        for (int j = 0; j < 8; ++j) acc[j] += br[r] * A[(size_t)r * D + d0 + j];
    }
    union { bf16x8 v; unsigned short s[8]; } ov;
    #pragma unroll
    for (int j = 0; j < 8; ++j) ov.s[j] = f2b(acc[j]);
    *(bf16x8*)(Weff + (size_t)o * D + d0) = ov.v;
}

// ---------------------------------------------------------------------------
// Fused GEMM: Y[m][n] = sum_k X_f32[m][k]*Wt_bf16[n][k] + bias[n]
//   x fp32 is converted to bf16 IN-KERNEL during A-staging (reg-staged:
//   global_load_dwordx4 -> f2b RNE -> ds_write_b128) -- bit-identical layout
//   and values to the old cvt_x + global_load_lds path, but skips one full
//   HBM round-trip (201 MB) and one kernel launch.
//
//   256x256 tile, BK=64, 8 waves (2Mx4N, 128x64/wave), 128 KiB LDS dbuf.
//   m201-style per-phase lockstep: 4 phases/tile, each
//     { ds_reads (+cvt/ds_writes) ; BARRIER ; lgkmcnt(0) ; setprio(1) ;
//       16 MFMA ; setprio(0) ; BARRIER }
//   Staging issued in P4 after the handoff barrier; counted vmcnt(12)
//   (= B(t+2) 4 gload_lds + A(t+2) 8 dwordx4) -- loads stay in flight
//   across barriers, never drained to 0 in the main loop.
//   A(t+1) regs are converted+written to the *other* LDS buffer in P2/P3
//   (that region was freed at iter t-1's handoff; nobody reads it in iter t).
// ---------------------------------------------------------------------------
template<int IB>
static __device__ __forceinline__ void mfma16(const bf16x8 (&aF)[4], const bf16x8 (&bF)[4],
                                              f32x4 (&acc)[8][4]) {
    __builtin_amdgcn_s_setprio(1);
    #pragma unroll
    for (int i = 0; i < 4; ++i)
        #pragma unroll
        for (int j = 0; j < 4; ++j)
            acc[IB + i][j] = __builtin_amdgcn_mfma_f32_16x16x32_bf16(aF[i], bF[j], acc[IB + i][j], 0, 0, 0);
    __builtin_amdgcn_s_setprio(0);
}

template<int Q>
static __device__ __forceinline__ void cvt_write(const f32x4 (&aStage)[8], ushort_t* nA, int tid) {
    union { bf16x8 v; unsigned short s[8]; } pk;
    #pragma unroll
    for (int e = 0; e < 4; ++e) pk.s[e]     = f2b(aStage[2 * Q][e]);
    #pragma unroll
    for (int e = 0; e < 4; ++e) pk.s[4 + e] = f2b(aStage[2 * Q + 1][e]);
    *(bf16x8*)(nA + tid * 8 + Q * 4096) = pk.v;
}

__global__ __launch_bounds__(512, 2) void gemm_fused(
    const float*    __restrict__ X,     // [M,K] fp32
    const ushort_t* __restrict__ Wt,    // [N,K] bf16 (Weff)
    const float*    __restrict__ bias,  // [N]   fp32
    float*          __restrict__ Y,     // [M,N] fp32
    int M, int N, int K)
{
    __shared__ __align__(16) ushort_t sA[2][BM * BK];   // 2 x 32 KB
    __shared__ __align__(16) ushort_t sB[2][BN * BK];   // 2 x 32 KB

    const int tid  = threadIdx.x;
    const int lane = tid & 63;
    const int wave = tid >> 6;
    const int wm   = wave >> 2;          // 0..1  -> rows [wm*128, +128)
    const int wn   = wave & 3;           // 0..3  -> cols [wn*64,  +64)

    // ---- XCD-aware tile assignment ----
    const int nT = N / BN;
    const int mT = M / BM;
    int mTile, nTile;
    if (((mT * nT) & 7) == 0 && (((mT * nT) >> 3) % nT) == 0) {
        const int xcd = blockIdx.x & 7;
        const int loc = blockIdx.x >> 3;
        const int mPerXcd = ((mT * nT) >> 3) / nT;
        mTile = xcd * mPerXcd + loc / nT;
        nTile = loc % nT;
    } else {
        nTile = blockIdx.x % nT;
        mTile = blockIdx.x / nT;
    }
    const int mBase = mTile * BM;
    const int nBase = nTile * BN;

    // ---- staging map: thread tid owns cell (row = tid>>3 + q*64, slot = tid&7);
    //      slot s of row r holds chunk s^(r&7)  (r&7 invariant under +64)
    const int sRow   = tid >> 3;
    const int sChunk = (tid & 7) ^ (sRow & 7);
    const float*    gA = X  + (size_t)(mBase + sRow) * K + sChunk * 8;
    const ushort_t* gB = Wt + (size_t)(nBase + sRow) * K + sChunk * 8;
    ushort_t* lB = &sB[0][0] + tid * 8;          // gload_lds dest (buf0); +BN*BK for buf1

    // ---- fragment read addressing ----
    const int fRow  = lane & 15;
    const int g     = lane >> 4;
    const int aBase = (wm * 128 + fRow) * BK;
    const int bBase = (wn * 64  + fRow) * BK;
    const int s0    = ((0 + g) ^ (lane & 7)) * 8;
    const int s1    = ((4 + g) ^ (lane & 7)) * 8;

    f32x4 acc[8][4];
    #pragma unroll
    for (int i = 0; i < 8; ++i)
        #pragma unroll
        for (int j = 0; j < 4; ++j)
            acc[i][j] = (f32x4){0.f, 0.f, 0.f, 0.f};

    f32x4 aStage[8];                              // 32 floats: next A tile, fp32
    const int nt = K / BK;

    // ---- prologue: B(0)->buf0; A(0)->regs; B(1)->buf1; cvt A(0)->buf0; A(1)->regs
    #pragma unroll
    for (int q = 0; q < 4; ++q)
        ld_g2l16(gB + (size_t)(q * 64) * K, lB + q * 4096);
    #pragma unroll
    for (int q = 0; q < 4; ++q) {
        aStage[2 * q]     = *(const f32x4*)(gA + (size_t)(q * 64) * K);
        aStage[2 * q + 1] = *(const f32x4*)(gA + (size_t)(q * 64) * K + 4);
    }
    #pragma unroll
    for (int q = 0; q < 4; ++q)
        ld_g2l16(gB + BK + (size_t)(q * 64) * K, lB + BN * BK + q * 4096);
    cvt_write<0>(aStage, &sA[0][0], tid);         // compiler inserts vmcnt for aStage
    cvt_write<1>(aStage, &sA[0][0], tid);
    cvt_write<2>(aStage, &sA[0][0], tid);
    cvt_write<3>(aStage, &sA[0][0], tid);
    #pragma unroll
    for (int q = 0; q < 4; ++q) {
        aStage[2 * q]     = *(const f32x4*)(gA + BK + (size_t)(q * 64) * K);
        aStage[2 * q + 1] = *(const f32x4*)(gA + BK + (size_t)(q * 64) * K + 4);
    }
    WAIT_VM(12);          // B(0) landed (B(1)+A(1)=12 newest stay in flight)
    WAIT_LGKM0();         // A(0) ds_writes done
    BARRIER();

    for (int t = 0; t < nt; ++t) {
        const ushort_t* pA = &sA[t & 1][0];
        const ushort_t* pB = &sB[t & 1][0];
        ushort_t* nA = &sA[(t + 1) & 1][0];
        const bool doCvt  = (t + 1 < nt);
        const bool doPref = (t + 2 < nt);

        bf16x8 aF[4], bF0[4], bF1[4];

        // ---- P1: bF0 + A rows 0..63 (ks0); MFMA quad (h0,ks0)
        #pragma unroll
        for (int j = 0; j < 4; ++j) bF0[j] = *(const bf16x8*)(pB + bBase + j * (16 * BK) + s0);
        #pragma unroll
        for (int i = 0; i < 4; ++i) aF[i] = *(const bf16x8*)(pA + aBase + i * (16 * BK) + s0);
        BARRIER(); WAIT_LGKM0();
        mfma16<0>(aF, bF0, acc);
        BARRIER();

        // ---- P2: A rows 64..127 (ks0); cvt+write A(t+1) q0,q1; MFMA (h1,ks0)
        #pragma unroll
        for (int i = 0; i < 4; ++i) aF[i] = *(const bf16x8*)(pA + aBase + (4 + i) * (16 * BK) + s0);
        if (doCvt) { cvt_write<0>(aStage, nA, tid); cvt_write<1>(aStage, nA, tid); }
        BARRIER(); WAIT_LGKM0();
        mfma16<4>(aF, bF0, acc);
        BARRIER();

        // ---- P3: bF1 + A rows 0..63 (ks1); cvt+write A(t+1) q2,q3; MFMA (h0,ks1)
        #pragma unroll
        for (int j = 0; j < 4; ++j) bF1[j] = *(const bf16x8*)(pB + bBase + j * (16 * BK) + s1);
        #pragma unroll
        for (int i = 0; i < 4; ++i) aF[i] = *(const bf16x8*)(pA + aBase + i * (16 * BK) + s1);
        if (doCvt) { cvt_write<2>(aStage, nA, tid); cvt_write<3>(aStage, nA, tid); }
        BARRIER(); WAIT_LGKM0();
        mfma16<0>(aF, bF1, acc);
        BARRIER();

        // ---- P4: A rows 64..127 (ks1); handoff; prefetch t+2; MFMA (h1,ks1)
        #pragma unroll
        for (int i = 0; i < 4; ++i) aF[i] = *(const bf16x8*)(pA + aBase + (4 + i) * (16 * BK) + s1);
        WAIT_LGKM0();     // this wave's reads of buf[t&1] complete
        BARRIER();        // ... for every wave -> buf[t&1] free to overwrite

        if (doPref) {
            ushort_t* lBn = &sB[t & 1][0] + tid * 8;
            #pragma unroll
            for (int q = 0; q < 4; ++q)
                ld_g2l16(gB + (size_t)(t + 2) * BK + (size_t)(q * 64) * K, lBn + q * 4096);
            const float* ga = gA + (size_t)(t + 2) * BK;
            #pragma unroll
            for (int q = 0; q < 4; ++q) {
                aStage[2 * q]     = *(const f32x4*)(ga + (size_t)(q * 64) * K);
                aStage[2 * q + 1] = *(const f32x4*)(ga + (size_t)(q * 64) * K + 4);
            }
        }
        mfma16<4>(aF, bF1, acc);

        if (doPref)      { WAIT_VM(12); BARRIER(); }   // B(t+1) landed; 12 newest in flight
        else if (doCvt)  { WAIT_VM(0);  BARRIER(); }   // tail: drain for last tile
        // t == nt-1: fall through to epilogue
    }

    // ---- epilogue: C/D layout col(n)=lane&15, row(m)=(lane>>4)*4+reg ----
    const int col  = lane & 15;
    const int rowq = (lane >> 4) * 4;
    #pragma unroll
    for (int j = 0; j < 4; ++j) {
        const int n    = nBase + wn * 64 + j * 16 + col;
        const float bv = bias[n];
        #pragma unroll
        for (int i = 0; i < 8; ++i) {
            const int mRow = mBase + wm * 128 + i * 16 + rowq;
            #pragma unroll
            for (int r = 0; r < 4; ++r)
                Y[(size_t)(mRow + r) * N + n] = acc[i][j][r] + bv;
        }
    }
}

// ---------------------------------------------------------------------------
// Fallback (only if ws too small / shapes odd): correct fused fp32 kernel.
// ---------------------------------------------------------------------------
__global__ __launch_bounds__(256) void fused_naive(
    const float* __restrict__ x, const float* __restrict__ W,
    const float* __restrict__ b, const float* __restrict__ A,
    const float* __restrict__ Bm, float* __restrict__ y, int D, int R)
{
    extern __shared__ float smem[];
    float* sx  = smem;
    float* red = smem + D;
    float* sh  = red + 256;
    const int tid = threadIdx.x;
    const int m   = blockIdx.x;

    for (int i = tid; i < D; i += 256) sx[i] = x[(size_t)m * D + i];
    __syncthreads();

    for (int r = 0; r < R; ++r) {
        float p = 0.f;
        for (int k = tid; k < D; k += 256) p += sx[k] * A[(size_t)r * D + k];
        red[tid] = p; __syncthreads();
        for (int s = 128; s > 0; s >>= 1) {
            if (tid < s) red[tid] += red[tid + s];
            __syncthreads();
        }
        if (tid == 0) sh[r] = red[0];
        __syncthreads();
    }

    for (int n = tid; n < D; n += 256) {
        float base = 0.f;
        const float* wr = W + (size_t)n * D;
        for (int k = 0; k < D; ++k) base += sx[k] * wr[k];
        float lora = 0.f;
        for (int r = 0; r < R; ++r) lora += sh[r] * Bm[(size_t)n * R + r];
        y[(size_t)m * D + n] = base + b[n] + SCALING * lora;
    }
}

extern "C" void kernel_launch(void* const* d_in, const int* in_sizes, int n_in,
                              void* d_out, int out_size, void* d_ws, size_t ws_size,
                              hipStream_t stream) {
    const float* x  = (const float*)d_in[0];
    const float* W  = (const float*)d_in[1];
    const float* b  = (const float*)d_in[2];
    const float* A  = (const float*)d_in[3];
    const float* Bm = (const float*)d_in[4];
    float* y = (float*)d_out;

    const int D = in_sizes[2];                 // 1024
    const int R = in_sizes[3] / D;             // 8
    const int M = in_sizes[0] / D;             // 32768
    (void)n_in; (void)out_size;

    const size_t weffBytes = (size_t)D * D * sizeof(ushort_t);   // 2 MB

    if (ws_size >= weffBytes &&
        (D % BN) == 0 && (M % BM) == 0 && (D % BK) == 0 && (D / BK) >= 2) {
        ushort_t* Weff = (ushort_t*)d_ws;

        int wthreads = D * (D / 8);
        weff_kernel<<<dim3((wthreads + 255) / 256), 256, 0, stream>>>(W, A, Bm, Weff, D, R);

        dim3 grid((M / BM) * (D / BN));        // 1D; kernel does XCD-aware remap
        gemm_fused<<<grid, 512, 0, stream>>>(x, Weff, b, y, M, D, D);
    } else {
        size_t shmem = (size_t)(D + 256 + R) * sizeof(float);
        fused_naive<<<dim3(M), 256, shmem, stream>>>(x, W, b, A, Bm, y, D, R);
    }
}

// Round 4
// 316.984 us; speedup vs baseline: 1.0530x; 1.0530x over previous
//
#include <hip/hip_runtime.h>
#include <stdint.h>

typedef unsigned short ushort_t;
typedef __attribute__((ext_vector_type(8))) short bf16x8;   // 8 bf16 = 4 VGPRs (MFMA A/B frag)
typedef __attribute__((ext_vector_type(4))) float f32x4;    // MFMA C/D frag / fp32 vec-load

#define BM 256
#define BN 256
#define BK 64
#define SCALING 2.0f

static __device__ __forceinline__ unsigned short f2b(float f) {
    union { float f; unsigned int i; } v;
    v.f = f;
    unsigned int r = 0x7FFFu + ((v.i >> 16) & 1u);   // round-to-nearest-even
    return (unsigned short)((v.i + r) >> 16);
}

// async global->LDS, 16 bytes/lane. HW dest = wave-uniform base + lane*16.
static __device__ __forceinline__ void ld_g2l16(const void* g, void* l) {
    __builtin_amdgcn_global_load_lds(
        (const __attribute__((address_space(1))) void*)g,
        (__attribute__((address_space(3))) void*)l,
        16, 0, 0);
}

#define SFENCE()     __builtin_amdgcn_sched_barrier(0)
#define BARRIER()    do { SFENCE(); __builtin_amdgcn_s_barrier(); SFENCE(); } while (0)
#define WAIT_LGKM0() do { asm volatile("s_waitcnt lgkmcnt(0)" ::: "memory"); SFENCE(); } while (0)
#define WAIT_VM(N)   do { asm volatile("s_waitcnt vmcnt(" #N ")" ::: "memory"); SFENCE(); } while (0)

// ---------------------------------------------------------------------------
// Kernel 1: W_eff[o][d] = W[o][d] + SCALING * sum_r B[o][r]*A[r][d]  (fp32 in, bf16 out RNE)
// ---------------------------------------------------------------------------
__global__ void weff_kernel(const float* __restrict__ W,
                            const float* __restrict__ A,
                            const float* __restrict__ Bm,
                            ushort_t* __restrict__ Weff,
                            int D, int R) {
    int gid = blockIdx.x * blockDim.x + threadIdx.x;
    int perRow = D >> 3;
    if (gid >= D * perRow) return;
    int o  = gid / perRow;
    int d0 = (gid - o * perRow) << 3;

    float br[16];
    for (int r = 0; r < R; ++r) br[r] = SCALING * Bm[(size_t)o * R + r];

    float acc[8];
    #pragma unroll
    for (int j = 0; j < 8; ++j) acc[j] = W[(size_t)o * D + d0 + j];
    for (int r = 0; r < R; ++r) {
        #pragma unroll
        for (int j = 0; j < 8; ++j) acc[j] += br[r] * A[(size_t)r * D + d0 + j];
    }
    union { bf16x8 v; unsigned short s[8]; } ov;
    #pragma unroll
    for (int j = 0; j < 8; ++j) ov.s[j] = f2b(acc[j]);
    *(bf16x8*)(Weff + (size_t)o * D + d0) = ov.v;
}

// ---------------------------------------------------------------------------
// Fused GEMM: Y[m][n] = sum_k X_f32[m][k]*Wt_bf16[n][k] + bias[n]
//   Schedule = round-1's measured-best 2-barrier-per-K-tile structure (89us)
//   with in-kernel fp32->bf16 A-conversion grafted at pressure-free points.
//
//   Per iter t (buffers: sA/sB[t&1] current, sA[(t+1)&1] being filled):
//     s1: cvt+ds_write A(t+1) -> sA[(t+1)&1]   (aStage consumed -> 32 VGPR free;
//         implicit vmcnt wait is a no-op: A(t+1) loads issued a full iter ago)
//     s2: issue A(t+2) fp32 -> aStage (8x dwordx4; ~1 iter of latency cover)
//         ds_read aF0[8], bF0[4], bF1[4]       (bF1 BEFORE handoff: sB[t&1]
//                                               is overwritten at s5)
//     s3: 32 MFMA ks0
//     s4: lgkm0 + BARRIER  (handoff: sB[t&1] free; cvt writes visible)
//     s5: stage B(t+2) -> sB[t&1]  (4x global_load_lds)
//     s6: ds_read aF1[8] from sA[t&1]          (safe: A prefetch targets the
//                                               OTHER buffer, regs only here)
//     s7: 32 MFMA ks1
//     s8: WAIT_VM(4)  -- drains B(t+1)+A(t+2), leaves B(t+2) riding the
//         barrier (counted vmcnt, never 0 in steady state); lgkm0 + BARRIER
//   vmcnt ledger: B(t) drained at iter t-1 s8 + barrier, read iter t s2. OK.
// ---------------------------------------------------------------------------
static __device__ __forceinline__ void mfma32(const bf16x8 (&aF)[8], const bf16x8 (&bF)[4],
                                              f32x4 (&acc)[8][4]) {
    __builtin_amdgcn_s_setprio(1);
    #pragma unroll
    for (int i = 0; i < 8; ++i)
        #pragma unroll
        for (int j = 0; j < 4; ++j)
            acc[i][j] = __builtin_amdgcn_mfma_f32_16x16x32_bf16(aF[i], bF[j], acc[i][j], 0, 0, 0);
    __builtin_amdgcn_s_setprio(0);
}

template<int Q>
static __device__ __forceinline__ void cvt_write(const f32x4 (&aStage)[8], ushort_t* nA, int tid) {
    union { bf16x8 v; unsigned short s[8]; } pk;
    #pragma unroll
    for (int e = 0; e < 4; ++e) pk.s[e]     = f2b(aStage[2 * Q][e]);
    #pragma unroll
    for (int e = 0; e < 4; ++e) pk.s[4 + e] = f2b(aStage[2 * Q + 1][e]);
    *(bf16x8*)(nA + tid * 8 + Q * 4096) = pk.v;
}

__global__ __launch_bounds__(512, 2) void gemm_fused(
    const float*    __restrict__ X,     // [M,K] fp32
    const ushort_t* __restrict__ Wt,    // [N,K] bf16 (Weff)
    const float*    __restrict__ bias,  // [N]   fp32
    float*          __restrict__ Y,     // [M,N] fp32
    int M, int N, int K)
{
    __shared__ __align__(16) ushort_t sA[2][BM * BK];   // 2 x 32 KB
    __shared__ __align__(16) ushort_t sB[2][BN * BK];   // 2 x 32 KB

    const int tid  = threadIdx.x;
    const int lane = tid & 63;
    const int wave = tid >> 6;
    const int wm   = wave >> 2;          // 0..1  -> rows [wm*128, +128)
    const int wn   = wave & 3;           // 0..3  -> cols [wn*64,  +64)

    // ---- XCD-aware tile assignment ----
    const int nT = N / BN;
    const int mT = M / BM;
    int mTile, nTile;
    if (((mT * nT) & 7) == 0 && (((mT * nT) >> 3) % nT) == 0) {
        const int xcd = blockIdx.x & 7;
        const int loc = blockIdx.x >> 3;
        const int mPerXcd = ((mT * nT) >> 3) / nT;
        mTile = xcd * mPerXcd + loc / nT;
        nTile = loc % nT;
    } else {
        nTile = blockIdx.x % nT;
        mTile = blockIdx.x / nT;
    }
    const int mBase = mTile * BM;
    const int nBase = nTile * BN;

    // ---- staging map: thread tid owns cell (row = tid>>3 + q*64, slot = tid&7);
    //      slot s of row r holds chunk s^(r&7)  (r&7 invariant under +64)
    const int sRow   = tid >> 3;
    const int sChunk = (tid & 7) ^ (sRow & 7);
    const float*    gA = X  + (size_t)(mBase + sRow) * K + sChunk * 8;
    const ushort_t* gB = Wt + (size_t)(nBase + sRow) * K + sChunk * 8;
    ushort_t* lB = &sB[0][0] + tid * 8;          // gload_lds dest (buf0); +BN*BK for buf1

    // ---- fragment read addressing ----
    const int fRow  = lane & 15;
    const int g     = lane >> 4;
    const int aBase = (wm * 128 + fRow) * BK;
    const int bBase = (wn * 64  + fRow) * BK;
    const int s0    = ((0 + g) ^ (lane & 7)) * 8;
    const int s1    = ((4 + g) ^ (lane & 7)) * 8;

    f32x4 acc[8][4];
    #pragma unroll
    for (int i = 0; i < 8; ++i)
        #pragma unroll
        for (int j = 0; j < 4; ++j)
            acc[i][j] = (f32x4){0.f, 0.f, 0.f, 0.f};

    f32x4 aStage[8];                              // 32 floats: next A tile, fp32
    const int nt = K / BK;

    // ---- prologue: B(0)->buf0, B(1)->buf1, A(0)->regs, cvt A(0)->sA[0]
    //      (implicit vmcnt wait on A(0) drains B(0),B(1) too), A(1)->regs.
    #pragma unroll
    for (int q = 0; q < 4; ++q)
        ld_g2l16(gB + (size_t)(q * 64) * K, lB + q * 4096);
    #pragma unroll
    for (int q = 0; q < 4; ++q)
        ld_g2l16(gB + BK + (size_t)(q * 64) * K, lB + BN * BK + q * 4096);
    #pragma unroll
    for (int q = 0; q < 4; ++q) {
        aStage[2 * q]     = *(const f32x4*)(gA + (size_t)(q * 64) * K);
        aStage[2 * q + 1] = *(const f32x4*)(gA + (size_t)(q * 64) * K + 4);
    }
    cvt_write<0>(aStage, &sA[0][0], tid);
    cvt_write<1>(aStage, &sA[0][0], tid);
    cvt_write<2>(aStage, &sA[0][0], tid);
    cvt_write<3>(aStage, &sA[0][0], tid);
    #pragma unroll
    for (int q = 0; q < 4; ++q) {
        aStage[2 * q]     = *(const f32x4*)(gA + BK + (size_t)(q * 64) * K);
        aStage[2 * q + 1] = *(const f32x4*)(gA + BK + (size_t)(q * 64) * K + 4);
    }
    WAIT_LGKM0();         // cvt ds_writes visible
    BARRIER();

    for (int t = 0; t < nt; ++t) {
        const ushort_t* pA = &sA[t & 1][0];
        const ushort_t* pB = &sB[t & 1][0];
        ushort_t* nA = &sA[(t + 1) & 1][0];

        // ---- s1: cvt+write A(t+1) (frees aStage) ----
        if (t + 1 < nt) {
            cvt_write<0>(aStage, nA, tid);
            cvt_write<1>(aStage, nA, tid);
            cvt_write<2>(aStage, nA, tid);
            cvt_write<3>(aStage, nA, tid);
        }
        // ---- s2: issue A(t+2) -> aStage; ds_read aF0, bF0, bF1 ----
        if (t + 2 < nt) {
            const float* ga = gA + (size_t)(t + 2) * BK;
            #pragma unroll
            for (int q = 0; q < 4; ++q) {
                aStage[2 * q]     = *(const f32x4*)(ga + (size_t)(q * 64) * K);
                aStage[2 * q + 1] = *(const f32x4*)(ga + (size_t)(q * 64) * K + 4);
            }
        }
        bf16x8 aF0[8], bF0[4], bF1[4];
        #pragma unroll
        for (int j = 0; j < 4; ++j) bF0[j] = *(const bf16x8*)(pB + bBase + j * (16 * BK) + s0);
        #pragma unroll
        for (int j = 0; j < 4; ++j) bF1[j] = *(const bf16x8*)(pB + bBase + j * (16 * BK) + s1);
        #pragma unroll
        for (int i = 0; i < 8; ++i) aF0[i] = *(const bf16x8*)(pA + aBase + i * (16 * BK) + s0);

        // ---- s3: MFMA ks0 (compiler inserts fine-grained lgkm waits) ----
        mfma32(aF0, bF0, acc);

        // ---- s4: handoff -- all waves' reads of sB[t&1] done; cvt writes done
        WAIT_LGKM0();
        BARRIER();

        // ---- s5: stage B(t+2) -> sB[t&1] ----
        if (t + 2 < nt) {
            ushort_t* lBn = &sB[t & 1][0] + tid * 8;
            #pragma unroll
            for (int q = 0; q < 4; ++q)
                ld_g2l16(gB + (size_t)(t + 2) * BK + (size_t)(q * 64) * K, lBn + q * 4096);
        }

        // ---- s6: ds_read aF1 from sA[t&1] (not overwritten this iter) ----
        bf16x8 aF1[8];
        #pragma unroll
        for (int i = 0; i < 8; ++i) aF1[i] = *(const bf16x8*)(pA + aBase + i * (16 * BK) + s1);

        // ---- s7: MFMA ks1 ----
        mfma32(aF1, bF1, acc);

        // ---- s8: counted drain + end barrier ----
        if (t + 2 < nt)      { WAIT_VM(4); }   // drain B(t+1)+A(t+2); B(t+2) rides
        else if (t + 1 < nt) { WAIT_VM(0); }   // tail: drain last B
        if (t + 1 < nt) { WAIT_LGKM0(); BARRIER(); }
    }

    // ---- epilogue: C/D layout col(n)=lane&15, row(m)=(lane>>4)*4+reg ----
    const int col  = lane & 15;
    const int rowq = (lane >> 4) * 4;
    #pragma unroll
    for (int j = 0; j < 4; ++j) {
        const int n    = nBase + wn * 64 + j * 16 + col;
        const float bv = bias[n];
        #pragma unroll
        for (int i = 0; i < 8; ++i) {
            const int mRow = mBase + wm * 128 + i * 16 + rowq;
            #pragma unroll
            for (int r = 0; r < 4; ++r)
                Y[(size_t)(mRow + r) * N + n] = acc[i][j][r] + bv;
        }
    }
}

// ---------------------------------------------------------------------------
// Fallback (only if ws too small / shapes odd): correct fused fp32 kernel.
// ---------------------------------------------------------------------------
__global__ __launch_bounds__(256) void fused_naive(
    const float* __restrict__ x, const float* __restrict__ W,
    const float* __restrict__ b, const float* __restrict__ A,
    const float* __restrict__ Bm, float* __restrict__ y, int D, int R)
{
    extern __shared__ float smem[];
    float* sx  = smem;
    float* red = smem + D;
    float* sh  = red + 256;
    const int tid = threadIdx.x;
    const int m   = blockIdx.x;

    for (int i = tid; i < D; i += 256) sx[i] = x[(size_t)m * D + i];
    __syncthreads();

    for (int r = 0; r < R; ++r) {
        float p = 0.f;
        for (int k = tid; k < D; k += 256) p += sx[k] * A[(size_t)r * D + k];
        red[tid] = p; __syncthreads();
        for (int s = 128; s > 0; s >>= 1) {
            if (tid < s) red[tid] += red[tid + s];
            __syncthreads();
        }
        if (tid == 0) sh[r] = red[0];
        __syncthreads();
    }

    for (int n = tid; n < D; n += 256) {
        float base = 0.f;
        const float* wr = W + (size_t)n * D;
        for (int k = 0; k < D; ++k) base += sx[k] * wr[k];
        float lora = 0.f;
        for (int r = 0; r < R; ++r) lora += sh[r] * Bm[(size_t)n * R + r];
        y[(size_t)m * D + n] = base + b[n] + SCALING * lora;
    }
}

extern "C" void kernel_launch(void* const* d_in, const int* in_sizes, int n_in,
                              void* d_out, int out_size, void* d_ws, size_t ws_size,
                              hipStream_t stream) {
    const float* x  = (const float*)d_in[0];
    const float* W  = (const float*)d_in[1];
    const float* b  = (const float*)d_in[2];
    const float* A  = (const float*)d_in[3];
    const float* Bm = (const float*)d_in[4];
    float* y = (float*)d_out;

    const int D = in_sizes[2];                 // 1024
    const int R = in_sizes[3] / D;             // 8
    const int M = in_sizes[0] / D;             // 32768
    (void)n_in; (void)out_size;

    const size_t weffBytes = (size_t)D * D * sizeof(ushort_t);   // 2 MB

    if (ws_size >= weffBytes &&
        (D % BN) == 0 && (M % BM) == 0 && (D % BK) == 0 && (D / BK) >= 2) {
        ushort_t* Weff = (ushort_t*)d_ws;

        int wthreads = D * (D / 8);
        weff_kernel<<<dim3((wthreads + 255) / 256), 256, 0, stream>>>(W, A, Bm, Weff, D, R);

        dim3 grid((M / BM) * (D / BN));        // 1D; kernel does XCD-aware remap
        gemm_fused<<<grid, 512, 0, stream>>>(x, Weff, b, y, M, D, D);
    } else {
        size_t shmem = (size_t)(D + 256 + R) * sizeof(float);
        fused_naive<<<dim3(M), 256, shmem, stream>>>(x, W, b, A, Bm, y, D, R);
    }
}